// Round 6
// baseline (125.279 us; speedup 1.0000x reference)
//
#include <hip/hip_runtime.h>

// CVXPolicy_Quadcopter: fused MLP (13->100 tanh ->12) + closed-form argmin via
// Lambert W. 1 element/thread, PHASE-SEPARATED for ILP:
//   phase 1: 25 independent pk-FMA accumulator pairs (v_pk_fma_f32)
//   phase 2: 50 independent v_exp_f32 (in-place on accumulators)
//   phase 3: shared-rcp tanh finish + 6 pk W2 accumulate chains
// Two halves of 25 pairs keep live VGPRs ~105 (4 waves/SIMD).
// ws layout (pack_weights, unchanged from R4):
//   region A: 50 rows x 32 floats: [pair(k=0)..pair(k=12), pair(b1'), pad x4]
//     (W1, b1 pre-scaled by 2*log2e so tanh uses exp2 with no multiply)
//   region B (+1600): 50 rows x 16 floats: [pair(m=0)..pair(m=5), pad x4]

constexpr int S = 12;   // z features
constexpr int H = 100;  // hidden
#define TWO_LOG2E 2.8853900817779268f

typedef float vf2 __attribute__((ext_vector_type(2)));

__device__ __forceinline__ float fast_rcp(float x) {
    return __builtin_amdgcn_rcpf(x);
}

__global__ __launch_bounds__(256) void pack_weights(
    const float* __restrict__ W1, const float* __restrict__ b1,
    const float* __restrict__ W2, float* __restrict__ ws)
{
    int idx = blockIdx.x * 256 + threadIdx.x;
    if (idx < 1600) {                        // region A: jp = idx/32, s = idx%32
        int jp = idx >> 5, s = idx & 31;
        float v = 0.0f;
        if (s < 26) {
            int k = s >> 1, half = s & 1;
            v = W1[k * H + 2 * jp + half] * TWO_LOG2E;
        } else if (s < 28) {
            int half = s & 1;
            v = b1[2 * jp + half] * TWO_LOG2E;
        }
        ws[idx] = v;
    } else if (idx < 2400) {                 // region B: jp = r/16, s = r%16
        int r = idx - 1600;
        int jp = r >> 4, s = r & 15;
        float v = 0.0f;
        if (s < 12) {
            int m = s >> 1, half = s & 1;
            v = W2[(2 * jp + half) * S + 6 + m];
        }
        ws[idx] = v;
    }
}

__global__ __launch_bounds__(256) void cvx_quad_kernel(
    const float* __restrict__ z, const float* __restrict__ t,
    const float* __restrict__ ws, const float* __restrict__ b2,
    float* __restrict__ out, int B)
{
    int i = blockIdx.x * 256 + threadIdx.x;
    if (i >= B) return;

    // Load input row: [t, z0..z11], materialize broadcast pairs once
    float inp[S + 1];
    inp[0] = t[i];
    const float4* zr = reinterpret_cast<const float4*>(z) + (size_t)i * 3;
    float4 a0 = zr[0], a1 = zr[1], a2 = zr[2];
    inp[1]  = a0.x; inp[2]  = a0.y; inp[3]  = a0.z; inp[4]  = a0.w;
    inp[5]  = a1.x; inp[6]  = a1.y; inp[7]  = a1.z; inp[8]  = a1.w;
    inp[9]  = a2.x; inp[10] = a2.y; inp[11] = a2.z; inp[12] = a2.w;
    vf2 inp2[S + 1];
    #pragma unroll
    for (int k = 0; k < S + 1; ++k) inp2[k] = (vf2){inp[k], inp[k]};

    // pk accumulators for p[6..11] (even/odd hidden-unit lanes)
    vf2 p[6];
    #pragma unroll
    for (int m = 0; m < 6; ++m) {
        float bm = b2[6 + m];
        p[m] = (vf2){bm, 0.0f};
    }

    #pragma unroll
    for (int h = 0; h < 2; ++h) {
        vf2 acc[25];

        // ---- phase 1: 25 independent preactivation pair chains ----
        #pragma unroll
        for (int q = 0; q < 25; ++q) {
            const vf2* wrow =
                reinterpret_cast<const vf2*>(ws + (h * 25 + q) * 32);
            vf2 a = wrow[13];                       // bias pair (pre-scaled)
            #pragma unroll
            for (int k = 0; k < S + 1; ++k)          // 13x v_pk_fma_f32
                a = __builtin_elementwise_fma(inp2[k], wrow[k], a);
            acc[q] = a;
        }

        // ---- phase 2: 50 independent exp2 (in-place) ----
        #pragma unroll
        for (int q = 0; q < 25; ++q) {
            acc[q] = (vf2){__builtin_amdgcn_exp2f(acc[q].x),
                           __builtin_amdgcn_exp2f(acc[q].y)};
        }

        // ---- phase 3: tanh finish (one rcp per pair) + W2 accumulate ----
        #pragma unroll
        for (int q = 0; q < 25; ++q) {
            vf2 ab = acc[q] + (vf2){1.0f, 1.0f};     // {a, b}
            float r = fast_rcp(ab.x * ab.y);         // one rcp per pair
            vf2 inv = (vf2){ab.y * r, ab.x * r};     // {1/a, 1/b}
            vf2 th = __builtin_elementwise_fma(
                (vf2){-2.0f, -2.0f}, inv, (vf2){1.0f, 1.0f});
            const vf2* qrow =
                reinterpret_cast<const vf2*>(ws + 1600 + (h * 25 + q) * 16);
            #pragma unroll
            for (int m = 0; m < 6; ++m)              // 6x v_pk_fma_f32
                p[m] = __builtin_elementwise_fma(th, qrow[m], p[m]);
        }
    }

    float p0 = p[0].x + p[0].y, p1 = p[1].x + p[1].y, p2 = p[2].x + p[2].y;
    float p3 = p[3].x + p[3].y, p4 = p[4].x + p[4].y, p5 = p[5].x + p[5].y;

    float c0 = 2.0f * (p0 + p1 + p2);  // / MASS, MASS = 0.5
    float c1 = p3, c2 = p4, c3 = p5;
    float x = fmaf(c0, c0, fmaf(c1, c1, fmaf(c2, c2, c3 * c3)));

    // Lambert W: solve w e^w = x, Newton from w0 = log(1+x)
    float w = __logf(1.0f + x);
    #pragma unroll
    for (int it = 0; it < 5; ++it) {
        float ew  = __expf(w);
        float num = fmaf(w, ew, -x);        // w*e^w - x
        float den = fmaf(ew, w, ew);        // e^w * (w + 1)
        w = w - num * fast_rcp(den);
    }

    float sc = -__expf(-0.5f * w);
    float4 o;
    o.x = c0 * sc;
    o.y = c1 * sc;
    o.z = c2 * sc;
    o.w = c3 * sc;
    reinterpret_cast<float4*>(out)[i] = o;
}

extern "C" void kernel_launch(void* const* d_in, const int* in_sizes, int n_in,
                              void* d_out, int out_size, void* d_ws, size_t ws_size,
                              hipStream_t stream) {
    const float* z  = (const float*)d_in[0];
    const float* t  = (const float*)d_in[1];
    const float* W1 = (const float*)d_in[2];
    const float* b1 = (const float*)d_in[3];
    const float* W2 = (const float*)d_in[4];
    const float* b2 = (const float*)d_in[5];
    float* out = (float*)d_out;
    float* ws  = (float*)d_ws;      // needs 2400 floats = 9.6 KB

    pack_weights<<<dim3(10), dim3(256), 0, stream>>>(W1, b1, W2, ws);

    int B = in_sizes[1];  // t has B elements
    int grid = (B + 255) / 256;
    cvx_quad_kernel<<<dim3(grid), dim3(256), 0, stream>>>(z, t, ws, b2, out, B);
}

// Round 7
// 104.443 us; speedup vs baseline: 1.1995x; 1.1995x over previous
//
#include <hip/hip_runtime.h>

// CVXPolicy_Quadcopter: fused MLP (13->100 tanh ->12) + closed-form argmin via
// Lambert W. 2 elements/thread x hidden-unit PAIRS (v_pk_fma_f32): each 160B
// of scalar weight fetch per jp now feeds 4 MACs/weight (2 elem x 2 units),
// halving SMEM-BW demand per FLOP (hypothesis: K$ BW is the R2-R4 ceiling).
// Rolled loop (unroll 2) keeps the body I-cache-hot; R5's phase split regressed.
// ws layout (pack_weights):
//   region A: 50 rows x 32 floats: [pair(k=0)..pair(k=12), pair(b1'), pad x4]
//     (W1, b1 pre-scaled by 2*log2e so tanh uses exp2 with no multiply)
//   region B (+1600): 50 rows x 16 floats: [pair(m=0)..pair(m=5), pad x4]

constexpr int S = 12;   // z features
constexpr int H = 100;  // hidden
#define TWO_LOG2E 2.8853900817779268f

typedef float vf2 __attribute__((ext_vector_type(2)));

__device__ __forceinline__ float fast_rcp(float x) {
    return __builtin_amdgcn_rcpf(x);
}

__global__ __launch_bounds__(256) void pack_weights(
    const float* __restrict__ W1, const float* __restrict__ b1,
    const float* __restrict__ W2, float* __restrict__ ws)
{
    int idx = blockIdx.x * 256 + threadIdx.x;
    if (idx < 1600) {                        // region A: jp = idx/32, s = idx%32
        int jp = idx >> 5, s = idx & 31;
        float v = 0.0f;
        if (s < 26) {
            int k = s >> 1, half = s & 1;
            v = W1[k * H + 2 * jp + half] * TWO_LOG2E;
        } else if (s < 28) {
            int half = s & 1;
            v = b1[2 * jp + half] * TWO_LOG2E;
        }
        ws[idx] = v;
    } else if (idx < 2400) {                 // region B: jp = r/16, s = r%16
        int r = idx - 1600;
        int jp = r >> 4, s = r & 15;
        float v = 0.0f;
        if (s < 12) {
            int m = s >> 1, half = s & 1;
            v = W2[(2 * jp + half) * S + 6 + m];
        }
        ws[idx] = v;
    }
}

__global__ __launch_bounds__(256) void cvx_quad_kernel(
    const float* __restrict__ z, const float* __restrict__ t,
    const float* __restrict__ ws, const float* __restrict__ b2,
    float* __restrict__ out, int B)
{
    int tid = blockIdx.x * 256 + threadIdx.x;
    int i0 = tid * 2;
    if (i0 >= B) return;

    // Load two input rows: [t, z0..z11]
    float inpA[S + 1], inpB[S + 1];
    inpA[0] = t[i0];
    inpB[0] = t[i0 + 1];
    const float4* zr = reinterpret_cast<const float4*>(z) + (size_t)i0 * 3;
    float4 a0 = zr[0], a1 = zr[1], a2 = zr[2];
    float4 d0 = zr[3], d1 = zr[4], d2 = zr[5];
    inpA[1]  = a0.x; inpA[2]  = a0.y; inpA[3]  = a0.z; inpA[4]  = a0.w;
    inpA[5]  = a1.x; inpA[6]  = a1.y; inpA[7]  = a1.z; inpA[8]  = a1.w;
    inpA[9]  = a2.x; inpA[10] = a2.y; inpA[11] = a2.z; inpA[12] = a2.w;
    inpB[1]  = d0.x; inpB[2]  = d0.y; inpB[3]  = d0.z; inpB[4]  = d0.w;
    inpB[5]  = d1.x; inpB[6]  = d1.y; inpB[7]  = d1.z; inpB[8]  = d1.w;
    inpB[9]  = d2.x; inpB[10] = d2.y; inpB[11] = d2.z; inpB[12] = d2.w;

    // pk accumulators for p[6..11], both elements
    vf2 pA[6], pB[6];
    #pragma unroll
    for (int m = 0; m < 6; ++m) {
        float bm = b2[6 + m];
        pA[m] = (vf2){bm, 0.0f};
        pB[m] = (vf2){bm, 0.0f};
    }

    #pragma unroll 2
    for (int jp = 0; jp < H / 2; ++jp) {
        const vf2* wrow = reinterpret_cast<const vf2*>(ws + jp * 32);
        vf2 bias = wrow[13];                 // (b1'_j, b1'_j1), pre-scaled
        vf2 accA = bias, accB = bias;
        #pragma unroll
        for (int k = 0; k < S + 1; ++k) {    // 2x 13 v_pk_fma_f32, shared wrow
            vf2 w = wrow[k];
            accA = __builtin_elementwise_fma((vf2){inpA[k], inpA[k]}, w, accA);
            accB = __builtin_elementwise_fma((vf2){inpB[k], inpB[k]}, w, accB);
        }

        // tanh(y), acc = 2*log2e*y: e = 2^acc; th = 1 - 2/(1+e); shared rcp
        float eA0 = __builtin_amdgcn_exp2f(accA.x);
        float eA1 = __builtin_amdgcn_exp2f(accA.y);
        float eB0 = __builtin_amdgcn_exp2f(accB.x);
        float eB1 = __builtin_amdgcn_exp2f(accB.y);
        vf2 abA = (vf2){eA0, eA1} + (vf2){1.0f, 1.0f};
        vf2 abB = (vf2){eB0, eB1} + (vf2){1.0f, 1.0f};
        float rA = fast_rcp(abA.x * abA.y);
        float rB = fast_rcp(abB.x * abB.y);
        vf2 invA = (vf2){abA.y, abA.x} * (vf2){rA, rA};
        vf2 invB = (vf2){abB.y, abB.x} * (vf2){rB, rB};
        vf2 thA = __builtin_elementwise_fma((vf2){-2.0f, -2.0f}, invA,
                                            (vf2){1.0f, 1.0f});
        vf2 thB = __builtin_elementwise_fma((vf2){-2.0f, -2.0f}, invB,
                                            (vf2){1.0f, 1.0f});

        const vf2* qrow = reinterpret_cast<const vf2*>(ws + 1600 + jp * 16);
        #pragma unroll
        for (int m = 0; m < 6; ++m) {        // 2x 6 v_pk_fma_f32, shared qrow
            vf2 q = qrow[m];
            pA[m] = __builtin_elementwise_fma(thA, q, pA[m]);
            pB[m] = __builtin_elementwise_fma(thB, q, pB[m]);
        }
    }

    #pragma unroll
    for (int e = 0; e < 2; ++e) {
        const vf2* p = e ? pB : pA;
        float p0 = p[0].x + p[0].y, p1 = p[1].x + p[1].y, p2 = p[2].x + p[2].y;
        float p3 = p[3].x + p[3].y, p4 = p[4].x + p[4].y, p5 = p[5].x + p[5].y;

        float c0 = 2.0f * (p0 + p1 + p2);  // / MASS, MASS = 0.5
        float c1 = p3, c2 = p4, c3 = p5;
        float x = fmaf(c0, c0, fmaf(c1, c1, fmaf(c2, c2, c3 * c3)));

        // Lambert W: solve w e^w = x, Newton from w0 = log(1+x)
        float w = __logf(1.0f + x);
        #pragma unroll
        for (int it = 0; it < 5; ++it) {
            float ew  = __expf(w);
            float num = fmaf(w, ew, -x);        // w*e^w - x
            float den = fmaf(ew, w, ew);        // e^w * (w + 1)
            w = w - num * fast_rcp(den);
        }

        float sc = -__expf(-0.5f * w);
        float4 o;
        o.x = c0 * sc;
        o.y = c1 * sc;
        o.z = c2 * sc;
        o.w = c3 * sc;
        reinterpret_cast<float4*>(out)[i0 + e] = o;
    }
}

extern "C" void kernel_launch(void* const* d_in, const int* in_sizes, int n_in,
                              void* d_out, int out_size, void* d_ws, size_t ws_size,
                              hipStream_t stream) {
    const float* z  = (const float*)d_in[0];
    const float* t  = (const float*)d_in[1];
    const float* W1 = (const float*)d_in[2];
    const float* b1 = (const float*)d_in[3];
    const float* W2 = (const float*)d_in[4];
    const float* b2 = (const float*)d_in[5];
    float* out = (float*)d_out;
    float* ws  = (float*)d_ws;      // needs 2400 floats = 9.6 KB

    pack_weights<<<dim3(10), dim3(256), 0, stream>>>(W1, b1, W2, ws);

    int B = in_sizes[1];  // t has B elements
    int threads = (B + 1) / 2;
    int grid = (threads + 255) / 256;
    cvx_quad_kernel<<<dim3(grid), dim3(256), 0, stream>>>(z, t, ws, b2, out, B);
}